// Round 11
// baseline (298.304 us; speedup 1.0000x reference)
//
#include <hip/hip_runtime.h>
#include <hip/hip_fp16.h>

#define N_NODES 100000
#define N_EDGES 1250000
#define HID 64
#define N_GRAPHS 512
#define OUT_CH 16

#define NSUP 196        // super-buckets of 512 nodes
#define SB_CAP 8192     // mean 6378, sigma ~80 -> +22σ
#define E_BLK 2048
#define NPB ((N_EDGES + E_BLK - 1) / E_BLK)  // 611
#define TILE2 ((N_NODES + 127) / 128)  // 782 blocks (2 row-tiles each)
#define NWP 6           // prepped weight matrices (W1a..W3b; W0 handled raw by lin)
#define TSTRIDE 68      // LDS T row stride (floats)
#define AGG_BLOCKS 3125 // 12500 waves x 8 rows = 100000 exactly
#define QCHUNKS 3125    // quarter-agg: 12500 waves = 4 planes x 3125 chunks x 32 rows

typedef _Float16 h16;
typedef _Float16 half2_t __attribute__((ext_vector_type(2)));
typedef _Float16 f16x8 __attribute__((ext_vector_type(8)));
typedef float f32x4 __attribute__((ext_vector_type(4)));

__device__ __forceinline__ void acc8(uint4 u, float* a) {
    half2_t h0 = __builtin_bit_cast(half2_t, u.x);
    half2_t h1 = __builtin_bit_cast(half2_t, u.y);
    half2_t h2 = __builtin_bit_cast(half2_t, u.z);
    half2_t h3 = __builtin_bit_cast(half2_t, u.w);
    a[0] += (float)h0[0]; a[1] += (float)h0[1];
    a[2] += (float)h1[0]; a[3] += (float)h1[1];
    a[4] += (float)h2[0]; a[5] += (float)h2[1];
    a[6] += (float)h3[0]; a[7] += (float)h3[1];
}

__device__ __forceinline__ unsigned pack2(float x, float y) {
    half2_t o;
    o[0] = (h16)x;
    o[1] = (h16)y;
    return __builtin_bit_cast(unsigned, o);
}

// ===========================================================================
// FAT kernel: partition (611 blks) || wprep (6 blks) || input-linear (782).
// r25: lin now writes QUARTER layout HQ[4][N][16] (plane = seg) — feeds the
// quarter-split layer-1 aggregate A/B probe. Otherwise verbatim r18.
// ===========================================================================
__global__ __launch_bounds__(256) void k_fat(const int* __restrict__ src,
                                             const int* __restrict__ dst,
                                             int* __restrict__ cnt,
                                             int* __restrict__ buckets,
                                             const float* __restrict__ W1a,
                                             const float* __restrict__ W1b,
                                             const float* __restrict__ W2a,
                                             const float* __restrict__ W2b,
                                             const float* __restrict__ W3a,
                                             const float* __restrict__ W3b,
                                             h16* __restrict__ WF,
                                             const float* __restrict__ W0,
                                             const float* __restrict__ B0,
                                             const float* __restrict__ Xin,
                                             h16* __restrict__ Hout) {
    __shared__ int hist[256];
    __shared__ int gbase[256];
    __shared__ int tsum[256];
    __shared__ __align__(16) int stage[E_BLK];
    __shared__ __align__(16) float sT[4 * 16 * TSTRIDE];

    int b = blockIdx.x;
    int t = threadIdx.x;

    if (b < NPB) {
        // ---------------- partition (r15 proven) ----------------
        int e0 = b * E_BLK;
        int eN = N_EDGES - e0;
        if (eN > E_BLK) eN = E_BLK;

        hist[t] = 0;
        __syncthreads();
        for (int i = t; i < eN; i += 256) atomicAdd(&hist[dst[e0 + i] >> 9], 1);
        __syncthreads();

        int c = hist[t];
        tsum[t] = c;
        __syncthreads();
        for (int off = 1; off < 256; off <<= 1) {
            int u = (t >= off) ? tsum[t - off] : 0;
            __syncthreads();
            tsum[t] += u;
            __syncthreads();
        }
        int pref = tsum[t] - c;
        if (t < NSUP && c > 0) gbase[t] = atomicAdd(&cnt[t], c);
        hist[t] = pref;
        __syncthreads();

        for (int i = t; i < eN; i += 256) {
            int s = src[e0 + i];
            int d = dst[e0 + i];
            int p = atomicAdd(&hist[d >> 9], 1);
            stage[p] = ((d & 511) << 17) | s;
        }
        __syncthreads();

        if (t < NSUP && c > 0) {
            int lstart = hist[t] - c;
            int gb = gbase[t];
            int cap = SB_CAP - gb;
            int n = c < cap ? c : (cap > 0 ? cap : 0);
            int* dp = buckets + (size_t)t * SB_CAP + gb;
            int r = 0;
            while (r < n && (((size_t)(dp + r)) & 15)) { dp[r] = stage[lstart + r]; ++r; }
            for (; r + 4 <= n; r += 4) {
                int4 v;
                v.x = stage[lstart + r];
                v.y = stage[lstart + r + 1];
                v.z = stage[lstart + r + 2];
                v.w = stage[lstart + r + 3];
                *(int4*)(dp + r) = v;
            }
            for (; r < n; ++r) dp[r] = stage[lstart + r];
        }
    } else if (b < NPB + NWP) {
        // ---------------- weight prep (W1a..W3b only) ----------------
        const float* Ws[NWP] = {W1a, W1b, W2a, W2b, W3a, W3b};
        const float* W = Ws[b - NPB];
        h16* dstW = WF + (size_t)(b - NPB) * 4096;
#pragma unroll
        for (int i = 0; i < 16; ++i) {
            int s = t + 256 * i;
            int k = s >> 6, col = s & 63;
            int kc = k >> 5, quad = (k >> 3) & 3, j = k & 7;
            int c = col >> 4, n = col & 15;
            dstW[((c * 2 + kc) * 4 + quad) * 128 + n * 8 + j] = (h16)W[s];
        }
    } else {
        // ---------------- input linear (r16 body, quarter-layout out) -------
        int lb = b - NPB - NWP;
        int w = t >> 6, lane = t & 63;
        int n16 = lane & 15, quad = lane >> 4;
        float* T = sT + w * 16 * TSTRIDE;

        f16x8 bw[4][2];
#pragma unroll
        for (int c = 0; c < 4; ++c)
#pragma unroll
            for (int kc = 0; kc < 2; ++kc) {
                f16x8 v;
#pragma unroll
                for (int j = 0; j < 8; ++j)
                    v[j] = (h16)W0[(kc * 32 + quad * 8 + j) * 64 + c * 16 + n16];
                bw[c][kc] = v;
            }
        float bv[4];
#pragma unroll
        for (int c = 0; c < 4; ++c) bv[c] = B0[c * 16 + n16];

#pragma unroll
        for (int tt = 0; tt < 2; ++tt) {
            int rbase = lb * 128 + tt * 64 + w * 16;
            int arow = rbase + n16;
            int crow = arow < N_NODES ? arow : N_NODES - 1;
            f16x8 a[2];
#pragma unroll
            for (int kc = 0; kc < 2; ++kc) {
                const float4* xp = (const float4*)(Xin + (size_t)crow * HID + kc * 32 + quad * 8);
                float4 p = xp[0], q = xp[1];
                f16x8 v;
                v[0] = (h16)p.x; v[1] = (h16)p.y; v[2] = (h16)p.z; v[3] = (h16)p.w;
                v[4] = (h16)q.x; v[5] = (h16)q.y; v[6] = (h16)q.z; v[7] = (h16)q.w;
                a[kc] = v;
            }

            f32x4 acc[4];
#pragma unroll
            for (int c = 0; c < 4; ++c) {
                acc[c] = (f32x4){bv[c], bv[c], bv[c], bv[c]};
#pragma unroll
                for (int kc = 0; kc < 2; ++kc)
                    acc[c] = __builtin_amdgcn_mfma_f32_16x16x32_f16(a[kc], bw[c][kc], acc[c], 0, 0, 0);
            }

#pragma unroll
            for (int c = 0; c < 4; ++c)
#pragma unroll
                for (int r = 0; r < 4; ++r)
                    T[(quad * 4 + r) * TSTRIDE + c * 16 + n16] = fmaxf(acc[c][r], 0.f);
            {
                int rl = lane >> 2, seg = lane & 3;
                int row = rbase + rl;
                if (row < N_NODES) {
                    const float* tr = &T[rl * TSTRIDE + seg * 16];
                    f16x8 o0, o1;
#pragma unroll
                    for (int i = 0; i < 8; ++i) {
                        o0[i] = (h16)tr[i];
                        o1[i] = (h16)tr[8 + i];
                    }
                    // quarter layout: plane seg holds channels [seg*16, seg*16+16)
                    h16* dp = Hout + (size_t)seg * N_NODES * 16 + (size_t)row * 16;
                    *(f16x8*)dp = o0;
                    *(f16x8*)(dp + 8) = o1;
                }
            }
        }
    }
}

// ===========================================================================
// Split (r15 proven): counting sort per super by 9-bit dstLocal. Unchanged.
// ===========================================================================
__global__ __launch_bounds__(256) void k_sort(const int* __restrict__ cnt,
                                              int* __restrict__ buckets,
                                              int* __restrict__ rowptrS) {
    __shared__ int srt[SB_CAP];   // 32 KB
    __shared__ int hist[512];
    __shared__ int curs[512];
    __shared__ int tsum[256];
    int s = blockIdx.x, t = threadIdx.x;
    int n = cnt[s];
    n = n < SB_CAP ? n : SB_CAP;
    int* gb = buckets + (size_t)s * SB_CAP;
    int sBase = s * SB_CAP;

    hist[t] = 0;
    hist[t + 256] = 0;
    __syncthreads();
    for (int i = t; i < n; i += 256) atomicAdd(&hist[gb[i] >> 17], 1);
    __syncthreads();

    int c0 = hist[2 * t], c1 = hist[2 * t + 1];
    int tot = c0 + c1;
    tsum[t] = tot;
    __syncthreads();
    for (int off = 1; off < 256; off <<= 1) {
        int u = (t >= off) ? tsum[t - off] : 0;
        __syncthreads();
        tsum[t] += u;
        __syncthreads();
    }
    int pref = tsum[t] - tot;
    curs[2 * t] = pref;
    curs[2 * t + 1] = pref + c0;
    rowptrS[s * 513 + 2 * t] = sBase + pref;
    rowptrS[s * 513 + 2 * t + 1] = sBase + pref + c0;
    if (t == 255) rowptrS[s * 513 + 512] = sBase + n;
    __syncthreads();

    for (int i = t; i < n; i += 256) {
        int rec = gb[i];
        int pos = atomicAdd(&curs[rec >> 17], 1);
        srt[pos] = rec;
    }
    __syncthreads();
    for (int i = t; i < n; i += 256) gb[i] = srt[i];
}

// ===========================================================================
// r25 QUARTER aggregate (layer-1 A/B probe): H split into 4 channel planes
// HQ[q][N][16] (3.2MB each — fits 4MB per-XCD L2). Same high-TLP schedule as
// r19: 12500 waves = 4 planes x 3125 chunks x 32 rows, 2 lanes x 16B per row,
// 8-deep pipelined random gathers. Bit-identical accumulation per channel.
// Discriminates: L3-miss-path limit (expect ~3x faster) vs L2-request-rate
// limit (expect ~3x slower; requests 4x at 32B grain).
// ===========================================================================
__global__ __launch_bounds__(256) void k_aggregate_q(const int* __restrict__ rowptrS,
                                                     const int* __restrict__ buckets,
                                                     const h16* __restrict__ Hq,
                                                     h16* __restrict__ Zq) {
    const uint4* H2 = (const uint4*)Hq;   // row-quarter = 2 x 16B
    uint4* Z2 = (uint4*)Zq;
    int lane = threadIdx.x & 63;
    int sub = lane & 1;                    // 16B half of the 32B row-quarter
    int grp = lane >> 1;                   // 0..31: row within chunk
    int gwave = (blockIdx.x * 256 + threadIdx.x) >> 6;   // 0..12499
    int q = gwave / QCHUNKS;
    int i = (gwave - q * QCHUNKS) * 32 + grp;            // < 100000 always
    size_t pb = (size_t)q * N_NODES * 2;                 // plane base (uint4)
    int s = i >> 9, l = i & 511;
    int start = rowptrS[s * 513 + l];
    int end = rowptrS[s * 513 + l + 1];
    float a[8] = {0.f, 0.f, 0.f, 0.f, 0.f, 0.f, 0.f, 0.f};
    acc8(H2[pb + (size_t)i * 2 + sub], a);
    int j = start;
    for (; j + 8 <= end; j += 8) {
        int s0 = buckets[j] & 0x1FFFF;
        int s1 = buckets[j + 1] & 0x1FFFF;
        int s2 = buckets[j + 2] & 0x1FFFF;
        int s3 = buckets[j + 3] & 0x1FFFF;
        int s4 = buckets[j + 4] & 0x1FFFF;
        int s5 = buckets[j + 5] & 0x1FFFF;
        int s6 = buckets[j + 6] & 0x1FFFF;
        int s7 = buckets[j + 7] & 0x1FFFF;
        uint4 u0 = H2[pb + (size_t)s0 * 2 + sub];
        uint4 u1 = H2[pb + (size_t)s1 * 2 + sub];
        uint4 u2 = H2[pb + (size_t)s2 * 2 + sub];
        uint4 u3 = H2[pb + (size_t)s3 * 2 + sub];
        uint4 u4 = H2[pb + (size_t)s4 * 2 + sub];
        uint4 u5 = H2[pb + (size_t)s5 * 2 + sub];
        uint4 u6 = H2[pb + (size_t)s6 * 2 + sub];
        uint4 u7 = H2[pb + (size_t)s7 * 2 + sub];
        acc8(u0, a); acc8(u1, a); acc8(u2, a); acc8(u3, a);
        acc8(u4, a); acc8(u5, a); acc8(u6, a); acc8(u7, a);
    }
    if (j + 4 <= end) {
        int s0 = buckets[j] & 0x1FFFF;
        int s1 = buckets[j + 1] & 0x1FFFF;
        int s2 = buckets[j + 2] & 0x1FFFF;
        int s3 = buckets[j + 3] & 0x1FFFF;
        uint4 u0 = H2[pb + (size_t)s0 * 2 + sub];
        uint4 u1 = H2[pb + (size_t)s1 * 2 + sub];
        uint4 u2 = H2[pb + (size_t)s2 * 2 + sub];
        uint4 u3 = H2[pb + (size_t)s3 * 2 + sub];
        acc8(u0, a); acc8(u1, a); acc8(u2, a); acc8(u3, a);
        j += 4;
    }
    if (j + 2 <= end) {
        int s0 = buckets[j] & 0x1FFFF;
        int s1 = buckets[j + 1] & 0x1FFFF;
        uint4 u0 = H2[pb + (size_t)s0 * 2 + sub];
        uint4 u1 = H2[pb + (size_t)s1 * 2 + sub];
        acc8(u0, a); acc8(u1, a);
        j += 2;
    }
    if (j < end) {
        int s0 = buckets[j] & 0x1FFFF;
        acc8(H2[pb + (size_t)s0 * 2 + sub], a);
    }
    uint4 o;
    o.x = pack2(a[0], a[1]);
    o.y = pack2(a[2], a[3]);
    o.z = pack2(a[4], a[5]);
    o.w = pack2(a[6], a[7]);
    Z2[pb + (size_t)i * 2 + sub] = o;
}

// ===========================================================================
// Aggregate (r19, measured best): layers 2-3. Unchanged.
// ===========================================================================
__global__ __launch_bounds__(256) void k_aggregate(const int* __restrict__ rowptrS,
                                                   const int* __restrict__ buckets,
                                                   const h16* __restrict__ H,
                                                   h16* __restrict__ Z) {
    const uint4* H8 = (const uint4*)H;   // row = 8 x 16B
    uint4* Z8 = (uint4*)Z;
    int lane = threadIdx.x & 63;
    int part = lane >> 3, sub = lane & 7;
    int gwave = (blockIdx.x * 256 + threadIdx.x) >> 6;
    int nw = (gridDim.x * 256) >> 6;
    for (int i0 = gwave * 8; i0 < N_NODES; i0 += nw * 8) {
        int i = i0 + part;
        bool valid = i < N_NODES;
        int iv = valid ? i : N_NODES - 1;
        int s = iv >> 9, l = iv & 511;
        int start = rowptrS[s * 513 + l];
        int end = valid ? rowptrS[s * 513 + l + 1] : start;
        float a[8] = {0.f, 0.f, 0.f, 0.f, 0.f, 0.f, 0.f, 0.f};
        acc8(H8[(size_t)iv * 8 + sub], a);
        int j = start;
        for (; j + 8 <= end; j += 8) {
            int s0 = buckets[j] & 0x1FFFF;
            int s1 = buckets[j + 1] & 0x1FFFF;
            int s2 = buckets[j + 2] & 0x1FFFF;
            int s3 = buckets[j + 3] & 0x1FFFF;
            int s4 = buckets[j + 4] & 0x1FFFF;
            int s5 = buckets[j + 5] & 0x1FFFF;
            int s6 = buckets[j + 6] & 0x1FFFF;
            int s7 = buckets[j + 7] & 0x1FFFF;
            uint4 u0 = H8[(size_t)s0 * 8 + sub];
            uint4 u1 = H8[(size_t)s1 * 8 + sub];
            uint4 u2 = H8[(size_t)s2 * 8 + sub];
            uint4 u3 = H8[(size_t)s3 * 8 + sub];
            uint4 u4 = H8[(size_t)s4 * 8 + sub];
            uint4 u5 = H8[(size_t)s5 * 8 + sub];
            uint4 u6 = H8[(size_t)s6 * 8 + sub];
            uint4 u7 = H8[(size_t)s7 * 8 + sub];
            acc8(u0, a);
            acc8(u1, a);
            acc8(u2, a);
            acc8(u3, a);
            acc8(u4, a);
            acc8(u5, a);
            acc8(u6, a);
            acc8(u7, a);
        }
        if (j + 4 <= end) {
            int s0 = buckets[j] & 0x1FFFF;
            int s1 = buckets[j + 1] & 0x1FFFF;
            int s2 = buckets[j + 2] & 0x1FFFF;
            int s3 = buckets[j + 3] & 0x1FFFF;
            uint4 u0 = H8[(size_t)s0 * 8 + sub];
            uint4 u1 = H8[(size_t)s1 * 8 + sub];
            uint4 u2 = H8[(size_t)s2 * 8 + sub];
            uint4 u3 = H8[(size_t)s3 * 8 + sub];
            acc8(u0, a);
            acc8(u1, a);
            acc8(u2, a);
            acc8(u3, a);
            j += 4;
        }
        if (j + 2 <= end) {
            int s0 = buckets[j] & 0x1FFFF;
            int s1 = buckets[j + 1] & 0x1FFFF;
            uint4 u0 = H8[(size_t)s0 * 8 + sub];
            uint4 u1 = H8[(size_t)s1 * 8 + sub];
            acc8(u0, a);
            acc8(u1, a);
            j += 2;
        }
        if (j < end) {
            int s0 = buckets[j] & 0x1FFFF;
            acc8(H8[(size_t)s0 * 8 + sub], a);
        }
        if (valid) {
            uint4 o;
            o.x = pack2(a[0], a[1]);
            o.y = pack2(a[2], a[3]);
            o.z = pack2(a[4], a[5]);
            o.w = pack2(a[6], a[7]);
            Z8[(size_t)i * 8 + sub] = o;
        }
    }
}

// ===========================================================================
// MFMA MLP (r16 proven) + qin flag: qin=1 reads quarter-layout Z (layer 1),
// qin=0 reads standard row-major Z (layers 2-3). Output always standard.
// ===========================================================================
__global__ __launch_bounds__(256) void k_mlp(const h16* __restrict__ WaF,
                                             const float* __restrict__ Ba,
                                             const h16* __restrict__ WbF,
                                             const float* __restrict__ Bb,
                                             const h16* __restrict__ Zin,
                                             h16* __restrict__ Hout,
                                             const int qin) {
    __shared__ __align__(16) float sT[4 * 16 * TSTRIDE];
    int t = threadIdx.x;
    int w = t >> 6, lane = t & 63;
    int n16 = lane & 15, quad = lane >> 4;
    float* T = sT + w * 16 * TSTRIDE;

    f16x8 bwa[4][2], bwb[4][2];
#pragma unroll
    for (int c = 0; c < 4; ++c)
#pragma unroll
        for (int kc = 0; kc < 2; ++kc) {
            int f = ((c * 2 + kc) * 4 + quad) * 128 + n16 * 8;
            bwa[c][kc] = *(const f16x8*)(WaF + f);
            bwb[c][kc] = *(const f16x8*)(WbF + f);
        }
    float bva[4], bvb[4];
#pragma unroll
    for (int c = 0; c < 4; ++c) {
        bva[c] = Ba[c * 16 + n16];
        bvb[c] = Bb[c * 16 + n16];
    }

#pragma unroll
    for (int tt = 0; tt < 2; ++tt) {
        int rbase = blockIdx.x * 128 + tt * 64 + w * 16;
        int arow = rbase + n16;
        int crow = arow < N_NODES ? arow : N_NODES - 1;
        f16x8 a0, a1;
        if (qin) {
            // quarter layout: ch quad*8..+7 -> plane quad>>1, off (quad&1)*8;
            // ch 32+quad*8 -> plane 2+(quad>>1), same offset.
            size_t off = (size_t)(quad >> 1) * N_NODES * 16 + (size_t)crow * 16 + (quad & 1) * 8;
            a0 = *(const f16x8*)(Zin + off);
            a1 = *(const f16x8*)(Zin + (size_t)2 * N_NODES * 16 + off);
        } else {
            const f16x8* zp = (const f16x8*)(Zin + (size_t)crow * HID + quad * 8);
            a0 = zp[0];
            a1 = zp[4];
        }

        f32x4 acc[4];
#pragma unroll
        for (int c = 0; c < 4; ++c) {
            acc[c] = (f32x4){bva[c], bva[c], bva[c], bva[c]};
            acc[c] = __builtin_amdgcn_mfma_f32_16x16x32_f16(a0, bwa[c][0], acc[c], 0, 0, 0);
            acc[c] = __builtin_amdgcn_mfma_f32_16x16x32_f16(a1, bwa[c][1], acc[c], 0, 0, 0);
        }

#pragma unroll
        for (int c = 0; c < 4; ++c)
#pragma unroll
            for (int r = 0; r < 4; ++r)
                T[(quad * 4 + r) * TSTRIDE + c * 16 + n16] = fmaxf(acc[c][r], 0.f);

        f16x8 ta[2];
#pragma unroll
        for (int kc = 0; kc < 2; ++kc) {
            float4 p = *(const float4*)&T[n16 * TSTRIDE + kc * 32 + quad * 8];
            float4 q = *(const float4*)&T[n16 * TSTRIDE + kc * 32 + quad * 8 + 4];
            f16x8 v;
            v[0] = (h16)p.x; v[1] = (h16)p.y; v[2] = (h16)p.z; v[3] = (h16)p.w;
            v[4] = (h16)q.x; v[5] = (h16)q.y; v[6] = (h16)q.z; v[7] = (h16)q.w;
            ta[kc] = v;
        }

#pragma unroll
        for (int c = 0; c < 4; ++c) {
            acc[c] = (f32x4){bvb[c], bvb[c], bvb[c], bvb[c]};
            acc[c] = __builtin_amdgcn_mfma_f32_16x16x32_f16(ta[0], bwb[c][0], acc[c], 0, 0, 0);
            acc[c] = __builtin_amdgcn_mfma_f32_16x16x32_f16(ta[1], bwb[c][1], acc[c], 0, 0, 0);
        }

#pragma unroll
        for (int c = 0; c < 4; ++c)
#pragma unroll
            for (int r = 0; r < 4; ++r)
                T[(quad * 4 + r) * TSTRIDE + c * 16 + n16] = fmaxf(acc[c][r], 0.f);
        {
            int rl = lane >> 2, seg = lane & 3;
            int row = rbase + rl;
            if (row < N_NODES) {
                const float* tr = &T[rl * TSTRIDE + seg * 16];
                f16x8 o0, o1;
#pragma unroll
                for (int i = 0; i < 8; ++i) {
                    o0[i] = (h16)tr[i];
                    o1[i] = (h16)tr[8 + i];
                }
                f16x8* dp = (f16x8*)(Hout + (size_t)row * HID + seg * 16);
                dp[0] = o0;
                dp[1] = o1;
            }
        }
    }
}

// ===========================================================================
// Fused mean-pool + readout (r16 proven). Unchanged (reads standard layout).
// ===========================================================================
__global__ __launch_bounds__(256) void k_poolfinal(const h16* __restrict__ H,
                                                   const int* __restrict__ batch,
                                                   const float* __restrict__ Wl,
                                                   const float* __restrict__ bl,
                                                   float* __restrict__ out) {
    __shared__ float sp[4 * HID];
    int g = blockIdx.x;
    int t = threadIdx.x;
    int lane = t & 63, w = t >> 6;
    int lo = 0, hi = N_NODES;
    while (lo < hi) { int m = (lo + hi) >> 1; if (batch[m] < g) lo = m + 1; else hi = m; }
    int start = lo;
    hi = N_NODES;
    while (lo < hi) { int m = (lo + hi) >> 1; if (batch[m] < g + 1) lo = m + 1; else hi = m; }
    int end = lo;
    float s0 = 0.f, s1 = 0.f, s2 = 0.f, s3 = 0.f;
    int r = start + w;
    for (; r + 12 < end; r += 16) {
        float v0 = (float)H[(size_t)r * HID + lane];
        float v1 = (float)H[(size_t)(r + 4) * HID + lane];
        float v2 = (float)H[(size_t)(r + 8) * HID + lane];
        float v3 = (float)H[(size_t)(r + 12) * HID + lane];
        s0 += v0; s1 += v1; s2 += v2; s3 += v3;
    }
    for (; r < end; r += 4) s0 += (float)H[(size_t)r * HID + lane];
    sp[w * HID + lane] = s0 + s1 + s2 + s3;
    __syncthreads();
    if (t < HID) {
        float tot = sp[t] + sp[HID + t] + sp[2 * HID + t] + sp[3 * HID + t];
        float c = (end > start) ? (float)(end - start) : 1.0f;
        sp[t] = tot / c;
    }
    __syncthreads();
    if (t < OUT_CH) {
        float acc = bl[t];
#pragma unroll
        for (int k = 0; k < HID; ++k) acc += sp[k] * Wl[k * OUT_CH + t];
        out[g * OUT_CH + t] = acc;
    }
}

extern "C" void kernel_launch(void* const* d_in, const int* in_sizes, int n_in,
                              void* d_out, int out_size, void* d_ws, size_t ws_size,
                              hipStream_t stream) {
    const float* x     = (const float*)d_in[0];
    const int*   edge  = (const int*)d_in[1];   // [2][N_EDGES] int32
    const int*   batch = (const int*)d_in[2];   // [N_NODES] int32 (sorted)
    const float* W0  = (const float*)d_in[3];
    const float* b0  = (const float*)d_in[4];
    const float* W1a = (const float*)d_in[5];
    const float* b1a = (const float*)d_in[6];
    const float* W1b = (const float*)d_in[7];
    const float* b1b = (const float*)d_in[8];
    const float* W2a = (const float*)d_in[9];
    const float* b2a = (const float*)d_in[10];
    const float* W2b = (const float*)d_in[11];
    const float* b2b = (const float*)d_in[12];
    const float* W3a = (const float*)d_in[13];
    const float* b3a = (const float*)d_in[14];
    const float* W3b = (const float*)d_in[15];
    const float* b3b = (const float*)d_in[16];
    const float* Wl  = (const float*)d_in[17];
    const float* bl  = (const float*)d_in[18];
    float* out = (float*)d_out;

    const int* src = edge;
    const int* dst = edge + N_EDGES;

    // Workspace: HA(fp16) | Z(fp16) | cnt | rowptrS | buckets | WF(fp16 x6)
    h16* HA = (h16*)d_ws;
    h16* Z  = HA + (size_t)N_NODES * HID;
    int* cnt     = (int*)(Z + (size_t)N_NODES * HID);
    int* rowptrS = cnt + NSUP;
    int* buckets = rowptrS + NSUP * 513;
    h16* WF      = (h16*)(buckets + (size_t)NSUP * SB_CAP);
    h16* W1aF = WF;               // order: W1a, W1b, W2a, W2b, W3a, W3b
    h16* W1bF = WF + 4096 * 1;
    h16* W2aF = WF + 4096 * 2;
    h16* W2bF = WF + 4096 * 3;
    h16* W3aF = WF + 4096 * 4;
    h16* W3bF = WF + 4096 * 5;

    hipMemsetAsync(cnt, 0, NSUP * sizeof(int), stream);
    // partition || wprep || input-linear(quarter-out) in one dispatch
    k_fat<<<NPB + NWP + TILE2, 256, 0, stream>>>(src, dst, cnt, buckets,
        W1a, W1b, W2a, W2b, W3a, W3b, WF, W0, b0, x, HA);
    k_sort<<<NSUP, 256, 0, stream>>>(cnt, buckets, rowptrS);

    // Layer 1: QUARTER-split probe (A arm)
    k_aggregate_q<<<AGG_BLOCKS, 256, 0, stream>>>(rowptrS, buckets, HA, Z);
    k_mlp<<<TILE2, 256, 0, stream>>>(W1aF, b1a, W1bF, b1b, Z, HA, 1);

    // Layers 2-3: standard r19 (B arm)
    k_aggregate<<<AGG_BLOCKS, 256, 0, stream>>>(rowptrS, buckets, HA, Z);
    k_mlp<<<TILE2, 256, 0, stream>>>(W2aF, b2a, W2bF, b2b, Z, HA, 0);

    k_aggregate<<<AGG_BLOCKS, 256, 0, stream>>>(rowptrS, buckets, HA, Z);
    k_mlp<<<TILE2, 256, 0, stream>>>(W3aF, b3a, W3bF, b3b, Z, HA, 0);

    k_poolfinal<<<N_GRAPHS, 256, 0, stream>>>(HA, batch, Wl, bl, out);
}

// Round 12
// 272.161 us; speedup vs baseline: 1.0961x; 1.0961x over previous
//
#include <hip/hip_runtime.h>
#include <hip/hip_fp16.h>

#define N_NODES 100000
#define N_EDGES 1250000
#define HID 64
#define N_GRAPHS 512
#define OUT_CH 16

#define NSUP 196        // super-buckets of 512 nodes
#define SB_CAP 8192     // mean 6378, sigma ~80 -> +22σ
#define E_BLK 2048
#define NPB ((N_EDGES + E_BLK - 1) / E_BLK)  // 611
#define TILE2 ((N_NODES + 127) / 128)  // 782 blocks (2 row-tiles each)
#define NWP 6           // prepped weight matrices (W1a..W3b; W0 handled raw by lin)
#define TSTRIDE 68      // LDS T row stride (floats)
#define AGG_BLOCKS 3125 // 12500 waves x 8 rows = 100000 exactly

typedef _Float16 h16;
typedef _Float16 half2_t __attribute__((ext_vector_type(2)));
typedef _Float16 f16x8 __attribute__((ext_vector_type(8)));
typedef float f32x4 __attribute__((ext_vector_type(4)));

__device__ __forceinline__ void acc8(uint4 u, float* a) {
    half2_t h0 = __builtin_bit_cast(half2_t, u.x);
    half2_t h1 = __builtin_bit_cast(half2_t, u.y);
    half2_t h2 = __builtin_bit_cast(half2_t, u.z);
    half2_t h3 = __builtin_bit_cast(half2_t, u.w);
    a[0] += (float)h0[0]; a[1] += (float)h0[1];
    a[2] += (float)h1[0]; a[3] += (float)h1[1];
    a[4] += (float)h2[0]; a[5] += (float)h2[1];
    a[6] += (float)h3[0]; a[7] += (float)h3[1];
}

__device__ __forceinline__ unsigned pack2(float x, float y) {
    half2_t o;
    o[0] = (h16)x;
    o[1] = (h16)y;
    return __builtin_bit_cast(unsigned, o);
}

// ===========================================================================
// FAT kernel (r18 proven): partition (611 blks) || wprep (6 blks) ||
// input-linear (782 blks) — mutually independent; one dispatch.
// ===========================================================================
__global__ __launch_bounds__(256) void k_fat(const int* __restrict__ src,
                                             const int* __restrict__ dst,
                                             int* __restrict__ cnt,
                                             int* __restrict__ buckets,
                                             const float* __restrict__ W1a,
                                             const float* __restrict__ W1b,
                                             const float* __restrict__ W2a,
                                             const float* __restrict__ W2b,
                                             const float* __restrict__ W3a,
                                             const float* __restrict__ W3b,
                                             h16* __restrict__ WF,
                                             const float* __restrict__ W0,
                                             const float* __restrict__ B0,
                                             const float* __restrict__ Xin,
                                             h16* __restrict__ Hout) {
    __shared__ int hist[256];
    __shared__ int gbase[256];
    __shared__ int tsum[256];
    __shared__ __align__(16) int stage[E_BLK];
    __shared__ __align__(16) float sT[4 * 16 * TSTRIDE];

    int b = blockIdx.x;
    int t = threadIdx.x;

    if (b < NPB) {
        // ---------------- partition (r15 proven) ----------------
        int e0 = b * E_BLK;
        int eN = N_EDGES - e0;
        if (eN > E_BLK) eN = E_BLK;

        hist[t] = 0;
        __syncthreads();
        for (int i = t; i < eN; i += 256) atomicAdd(&hist[dst[e0 + i] >> 9], 1);
        __syncthreads();

        int c = hist[t];
        tsum[t] = c;
        __syncthreads();
        for (int off = 1; off < 256; off <<= 1) {
            int u = (t >= off) ? tsum[t - off] : 0;
            __syncthreads();
            tsum[t] += u;
            __syncthreads();
        }
        int pref = tsum[t] - c;
        if (t < NSUP && c > 0) gbase[t] = atomicAdd(&cnt[t], c);
        hist[t] = pref;
        __syncthreads();

        for (int i = t; i < eN; i += 256) {
            int s = src[e0 + i];
            int d = dst[e0 + i];
            int p = atomicAdd(&hist[d >> 9], 1);
            stage[p] = ((d & 511) << 17) | s;
        }
        __syncthreads();

        if (t < NSUP && c > 0) {
            int lstart = hist[t] - c;
            int gb = gbase[t];
            int cap = SB_CAP - gb;
            int n = c < cap ? c : (cap > 0 ? cap : 0);
            int* dp = buckets + (size_t)t * SB_CAP + gb;
            int r = 0;
            while (r < n && (((size_t)(dp + r)) & 15)) { dp[r] = stage[lstart + r]; ++r; }
            for (; r + 4 <= n; r += 4) {
                int4 v;
                v.x = stage[lstart + r];
                v.y = stage[lstart + r + 1];
                v.z = stage[lstart + r + 2];
                v.w = stage[lstart + r + 3];
                *(int4*)(dp + r) = v;
            }
            for (; r < n; ++r) dp[r] = stage[lstart + r];
        }
    } else if (b < NPB + NWP) {
        // ---------------- weight prep (W1a..W3b only) ----------------
        const float* Ws[NWP] = {W1a, W1b, W2a, W2b, W3a, W3b};
        const float* W = Ws[b - NPB];
        h16* dstW = WF + (size_t)(b - NPB) * 4096;
#pragma unroll
        for (int i = 0; i < 16; ++i) {
            int s = t + 256 * i;
            int k = s >> 6, col = s & 63;
            int kc = k >> 5, quad = (k >> 3) & 3, j = k & 7;
            int c = col >> 4, n = col & 15;
            dstW[((c * 2 + kc) * 4 + quad) * 128 + n * 8 + j] = (h16)W[s];
        }
    } else {
        // ---------------- input linear (r16), raw-W0 fragment load ----------
        int lb = b - NPB - NWP;
        int w = t >> 6, lane = t & 63;
        int n16 = lane & 15, quad = lane >> 4;
        float* T = sT + w * 16 * TSTRIDE;

        f16x8 bw[4][2];
#pragma unroll
        for (int c = 0; c < 4; ++c)
#pragma unroll
            for (int kc = 0; kc < 2; ++kc) {
                f16x8 v;
#pragma unroll
                for (int j = 0; j < 8; ++j)
                    v[j] = (h16)W0[(kc * 32 + quad * 8 + j) * 64 + c * 16 + n16];
                bw[c][kc] = v;
            }
        float bv[4];
#pragma unroll
        for (int c = 0; c < 4; ++c) bv[c] = B0[c * 16 + n16];

#pragma unroll
        for (int tt = 0; tt < 2; ++tt) {
            int rbase = lb * 128 + tt * 64 + w * 16;
            int arow = rbase + n16;
            int crow = arow < N_NODES ? arow : N_NODES - 1;
            f16x8 a[2];
#pragma unroll
            for (int kc = 0; kc < 2; ++kc) {
                const float4* xp = (const float4*)(Xin + (size_t)crow * HID + kc * 32 + quad * 8);
                float4 p = xp[0], q = xp[1];
                f16x8 v;
                v[0] = (h16)p.x; v[1] = (h16)p.y; v[2] = (h16)p.z; v[3] = (h16)p.w;
                v[4] = (h16)q.x; v[5] = (h16)q.y; v[6] = (h16)q.z; v[7] = (h16)q.w;
                a[kc] = v;
            }

            f32x4 acc[4];
#pragma unroll
            for (int c = 0; c < 4; ++c) {
                acc[c] = (f32x4){bv[c], bv[c], bv[c], bv[c]};
#pragma unroll
                for (int kc = 0; kc < 2; ++kc)
                    acc[c] = __builtin_amdgcn_mfma_f32_16x16x32_f16(a[kc], bw[c][kc], acc[c], 0, 0, 0);
            }

#pragma unroll
            for (int c = 0; c < 4; ++c)
#pragma unroll
                for (int r = 0; r < 4; ++r)
                    T[(quad * 4 + r) * TSTRIDE + c * 16 + n16] = fmaxf(acc[c][r], 0.f);
            {
                int rl = lane >> 2, seg = lane & 3;
                int row = rbase + rl;
                if (row < N_NODES) {
                    const float* tr = &T[rl * TSTRIDE + seg * 16];
                    f16x8 o0, o1;
#pragma unroll
                    for (int i = 0; i < 8; ++i) {
                        o0[i] = (h16)tr[i];
                        o1[i] = (h16)tr[8 + i];
                    }
                    f16x8* dp = (f16x8*)(Hout + (size_t)row * HID + seg * 16);
                    dp[0] = o0;
                    dp[1] = o1;
                }
            }
        }
    }
}

// ===========================================================================
// Split (r15 proven): counting sort per super by 9-bit dstLocal. Unchanged.
// ===========================================================================
__global__ __launch_bounds__(256) void k_sort(const int* __restrict__ cnt,
                                              int* __restrict__ buckets,
                                              int* __restrict__ rowptrS) {
    __shared__ int srt[SB_CAP];   // 32 KB
    __shared__ int hist[512];
    __shared__ int curs[512];
    __shared__ int tsum[256];
    int s = blockIdx.x, t = threadIdx.x;
    int n = cnt[s];
    n = n < SB_CAP ? n : SB_CAP;
    int* gb = buckets + (size_t)s * SB_CAP;
    int sBase = s * SB_CAP;

    hist[t] = 0;
    hist[t + 256] = 0;
    __syncthreads();
    for (int i = t; i < n; i += 256) atomicAdd(&hist[gb[i] >> 17], 1);
    __syncthreads();

    int c0 = hist[2 * t], c1 = hist[2 * t + 1];
    int tot = c0 + c1;
    tsum[t] = tot;
    __syncthreads();
    for (int off = 1; off < 256; off <<= 1) {
        int u = (t >= off) ? tsum[t - off] : 0;
        __syncthreads();
        tsum[t] += u;
        __syncthreads();
    }
    int pref = tsum[t] - tot;
    curs[2 * t] = pref;
    curs[2 * t + 1] = pref + c0;
    rowptrS[s * 513 + 2 * t] = sBase + pref;
    rowptrS[s * 513 + 2 * t + 1] = sBase + pref + c0;
    if (t == 255) rowptrS[s * 513 + 512] = sBase + n;
    __syncthreads();

    for (int i = t; i < n; i += 256) {
        int rec = gb[i];
        int pos = atomicAdd(&curs[rec >> 17], 1);
        srt[pos] = rec;
    }
    __syncthreads();
    for (int i = t; i < n; i += 256) gb[i] = srt[i];
}

// ===========================================================================
// Aggregate (r19, measured best): 8 rows/wave, 8 lanes x 16B (dwordx4),
// 8-deep pipelined gathers, 12500 waves. At the random-request service-rate
// floor (r25 probe: time invariant to cache residency and fetch bytes).
// ===========================================================================
__global__ __launch_bounds__(256) void k_aggregate(const int* __restrict__ rowptrS,
                                                   const int* __restrict__ buckets,
                                                   const h16* __restrict__ H,
                                                   h16* __restrict__ Z) {
    const uint4* H8 = (const uint4*)H;   // row = 8 x 16B
    uint4* Z8 = (uint4*)Z;
    int lane = threadIdx.x & 63;
    int part = lane >> 3, sub = lane & 7;
    int gwave = (blockIdx.x * 256 + threadIdx.x) >> 6;
    int nw = (gridDim.x * 256) >> 6;
    for (int i0 = gwave * 8; i0 < N_NODES; i0 += nw * 8) {
        int i = i0 + part;
        bool valid = i < N_NODES;
        int iv = valid ? i : N_NODES - 1;
        int s = iv >> 9, l = iv & 511;
        int start = rowptrS[s * 513 + l];
        int end = valid ? rowptrS[s * 513 + l + 1] : start;
        float a[8] = {0.f, 0.f, 0.f, 0.f, 0.f, 0.f, 0.f, 0.f};
        acc8(H8[(size_t)iv * 8 + sub], a);
        int j = start;
        for (; j + 8 <= end; j += 8) {
            int s0 = buckets[j] & 0x1FFFF;
            int s1 = buckets[j + 1] & 0x1FFFF;
            int s2 = buckets[j + 2] & 0x1FFFF;
            int s3 = buckets[j + 3] & 0x1FFFF;
            int s4 = buckets[j + 4] & 0x1FFFF;
            int s5 = buckets[j + 5] & 0x1FFFF;
            int s6 = buckets[j + 6] & 0x1FFFF;
            int s7 = buckets[j + 7] & 0x1FFFF;
            uint4 u0 = H8[(size_t)s0 * 8 + sub];
            uint4 u1 = H8[(size_t)s1 * 8 + sub];
            uint4 u2 = H8[(size_t)s2 * 8 + sub];
            uint4 u3 = H8[(size_t)s3 * 8 + sub];
            uint4 u4 = H8[(size_t)s4 * 8 + sub];
            uint4 u5 = H8[(size_t)s5 * 8 + sub];
            uint4 u6 = H8[(size_t)s6 * 8 + sub];
            uint4 u7 = H8[(size_t)s7 * 8 + sub];
            acc8(u0, a);
            acc8(u1, a);
            acc8(u2, a);
            acc8(u3, a);
            acc8(u4, a);
            acc8(u5, a);
            acc8(u6, a);
            acc8(u7, a);
        }
        if (j + 4 <= end) {
            int s0 = buckets[j] & 0x1FFFF;
            int s1 = buckets[j + 1] & 0x1FFFF;
            int s2 = buckets[j + 2] & 0x1FFFF;
            int s3 = buckets[j + 3] & 0x1FFFF;
            uint4 u0 = H8[(size_t)s0 * 8 + sub];
            uint4 u1 = H8[(size_t)s1 * 8 + sub];
            uint4 u2 = H8[(size_t)s2 * 8 + sub];
            uint4 u3 = H8[(size_t)s3 * 8 + sub];
            acc8(u0, a);
            acc8(u1, a);
            acc8(u2, a);
            acc8(u3, a);
            j += 4;
        }
        if (j + 2 <= end) {
            int s0 = buckets[j] & 0x1FFFF;
            int s1 = buckets[j + 1] & 0x1FFFF;
            uint4 u0 = H8[(size_t)s0 * 8 + sub];
            uint4 u1 = H8[(size_t)s1 * 8 + sub];
            acc8(u0, a);
            acc8(u1, a);
            j += 2;
        }
        if (j < end) {
            int s0 = buckets[j] & 0x1FFFF;
            acc8(H8[(size_t)s0 * 8 + sub], a);
        }
        if (valid) {
            uint4 o;
            o.x = pack2(a[0], a[1]);
            o.y = pack2(a[2], a[3]);
            o.z = pack2(a[4], a[5]);
            o.w = pack2(a[6], a[7]);
            Z8[(size_t)i * 8 + sub] = o;
        }
    }
}

// ===========================================================================
// MFMA MLP (r16 proven): 2 row-tiles (128 rows) per block, B-frags reused.
// ===========================================================================
__global__ __launch_bounds__(256) void k_mlp(const h16* __restrict__ WaF,
                                             const float* __restrict__ Ba,
                                             const h16* __restrict__ WbF,
                                             const float* __restrict__ Bb,
                                             const h16* __restrict__ Zin,
                                             h16* __restrict__ Hout) {
    __shared__ __align__(16) float sT[4 * 16 * TSTRIDE];
    int t = threadIdx.x;
    int w = t >> 6, lane = t & 63;
    int n16 = lane & 15, quad = lane >> 4;
    float* T = sT + w * 16 * TSTRIDE;

    f16x8 bwa[4][2], bwb[4][2];
#pragma unroll
    for (int c = 0; c < 4; ++c)
#pragma unroll
        for (int kc = 0; kc < 2; ++kc) {
            int f = ((c * 2 + kc) * 4 + quad) * 128 + n16 * 8;
            bwa[c][kc] = *(const f16x8*)(WaF + f);
            bwb[c][kc] = *(const f16x8*)(WbF + f);
        }
    float bva[4], bvb[4];
#pragma unroll
    for (int c = 0; c < 4; ++c) {
        bva[c] = Ba[c * 16 + n16];
        bvb[c] = Bb[c * 16 + n16];
    }

#pragma unroll
    for (int tt = 0; tt < 2; ++tt) {
        int rbase = blockIdx.x * 128 + tt * 64 + w * 16;
        int arow = rbase + n16;
        int crow = arow < N_NODES ? arow : N_NODES - 1;
        const f16x8* zp = (const f16x8*)(Zin + (size_t)crow * HID + quad * 8);
        f16x8 a0 = zp[0];
        f16x8 a1 = zp[4];

        f32x4 acc[4];
#pragma unroll
        for (int c = 0; c < 4; ++c) {
            acc[c] = (f32x4){bva[c], bva[c], bva[c], bva[c]};
            acc[c] = __builtin_amdgcn_mfma_f32_16x16x32_f16(a0, bwa[c][0], acc[c], 0, 0, 0);
            acc[c] = __builtin_amdgcn_mfma_f32_16x16x32_f16(a1, bwa[c][1], acc[c], 0, 0, 0);
        }

#pragma unroll
        for (int c = 0; c < 4; ++c)
#pragma unroll
            for (int r = 0; r < 4; ++r)
                T[(quad * 4 + r) * TSTRIDE + c * 16 + n16] = fmaxf(acc[c][r], 0.f);

        f16x8 ta[2];
#pragma unroll
        for (int kc = 0; kc < 2; ++kc) {
            float4 p = *(const float4*)&T[n16 * TSTRIDE + kc * 32 + quad * 8];
            float4 q = *(const float4*)&T[n16 * TSTRIDE + kc * 32 + quad * 8 + 4];
            f16x8 v;
            v[0] = (h16)p.x; v[1] = (h16)p.y; v[2] = (h16)p.z; v[3] = (h16)p.w;
            v[4] = (h16)q.x; v[5] = (h16)q.y; v[6] = (h16)q.z; v[7] = (h16)q.w;
            ta[kc] = v;
        }

#pragma unroll
        for (int c = 0; c < 4; ++c) {
            acc[c] = (f32x4){bvb[c], bvb[c], bvb[c], bvb[c]};
            acc[c] = __builtin_amdgcn_mfma_f32_16x16x32_f16(ta[0], bwb[c][0], acc[c], 0, 0, 0);
            acc[c] = __builtin_amdgcn_mfma_f32_16x16x32_f16(ta[1], bwb[c][1], acc[c], 0, 0, 0);
        }

#pragma unroll
        for (int c = 0; c < 4; ++c)
#pragma unroll
            for (int r = 0; r < 4; ++r)
                T[(quad * 4 + r) * TSTRIDE + c * 16 + n16] = fmaxf(acc[c][r], 0.f);
        {
            int rl = lane >> 2, seg = lane & 3;
            int row = rbase + rl;
            if (row < N_NODES) {
                const float* tr = &T[rl * TSTRIDE + seg * 16];
                f16x8 o0, o1;
#pragma unroll
                for (int i = 0; i < 8; ++i) {
                    o0[i] = (h16)tr[i];
                    o1[i] = (h16)tr[8 + i];
                }
                f16x8* dp = (f16x8*)(Hout + (size_t)row * HID + seg * 16);
                dp[0] = o0;
                dp[1] = o1;
            }
        }
    }
}

// ===========================================================================
// Fused mean-pool + readout (r16 proven). Unchanged.
// ===========================================================================
__global__ __launch_bounds__(256) void k_poolfinal(const h16* __restrict__ H,
                                                   const int* __restrict__ batch,
                                                   const float* __restrict__ Wl,
                                                   const float* __restrict__ bl,
                                                   float* __restrict__ out) {
    __shared__ float sp[4 * HID];
    int g = blockIdx.x;
    int t = threadIdx.x;
    int lane = t & 63, w = t >> 6;
    int lo = 0, hi = N_NODES;
    while (lo < hi) { int m = (lo + hi) >> 1; if (batch[m] < g) lo = m + 1; else hi = m; }
    int start = lo;
    hi = N_NODES;
    while (lo < hi) { int m = (lo + hi) >> 1; if (batch[m] < g + 1) lo = m + 1; else hi = m; }
    int end = lo;
    float s0 = 0.f, s1 = 0.f, s2 = 0.f, s3 = 0.f;
    int r = start + w;
    for (; r + 12 < end; r += 16) {
        float v0 = (float)H[(size_t)r * HID + lane];
        float v1 = (float)H[(size_t)(r + 4) * HID + lane];
        float v2 = (float)H[(size_t)(r + 8) * HID + lane];
        float v3 = (float)H[(size_t)(r + 12) * HID + lane];
        s0 += v0; s1 += v1; s2 += v2; s3 += v3;
    }
    for (; r < end; r += 4) s0 += (float)H[(size_t)r * HID + lane];
    sp[w * HID + lane] = s0 + s1 + s2 + s3;
    __syncthreads();
    if (t < HID) {
        float tot = sp[t] + sp[HID + t] + sp[2 * HID + t] + sp[3 * HID + t];
        float c = (end > start) ? (float)(end - start) : 1.0f;
        sp[t] = tot / c;
    }
    __syncthreads();
    if (t < OUT_CH) {
        float acc = bl[t];
#pragma unroll
        for (int k = 0; k < HID; ++k) acc += sp[k] * Wl[k * OUT_CH + t];
        out[g * OUT_CH + t] = acc;
    }
}

extern "C" void kernel_launch(void* const* d_in, const int* in_sizes, int n_in,
                              void* d_out, int out_size, void* d_ws, size_t ws_size,
                              hipStream_t stream) {
    const float* x     = (const float*)d_in[0];
    const int*   edge  = (const int*)d_in[1];   // [2][N_EDGES] int32
    const int*   batch = (const int*)d_in[2];   // [N_NODES] int32 (sorted)
    const float* W0  = (const float*)d_in[3];
    const float* b0  = (const float*)d_in[4];
    const float* W1a = (const float*)d_in[5];
    const float* b1a = (const float*)d_in[6];
    const float* W1b = (const float*)d_in[7];
    const float* b1b = (const float*)d_in[8];
    const float* W2a = (const float*)d_in[9];
    const float* b2a = (const float*)d_in[10];
    const float* W2b = (const float*)d_in[11];
    const float* b2b = (const float*)d_in[12];
    const float* W3a = (const float*)d_in[13];
    const float* b3a = (const float*)d_in[14];
    const float* W3b = (const float*)d_in[15];
    const float* b3b = (const float*)d_in[16];
    const float* Wl  = (const float*)d_in[17];
    const float* bl  = (const float*)d_in[18];
    float* out = (float*)d_out;

    const int* src = edge;
    const int* dst = edge + N_EDGES;

    // Workspace: HA(fp16) | Z(fp16) | cnt | rowptrS | buckets | WF(fp16 x6)
    h16* HA = (h16*)d_ws;
    h16* Z  = HA + (size_t)N_NODES * HID;
    int* cnt     = (int*)(Z + (size_t)N_NODES * HID);
    int* rowptrS = cnt + NSUP;
    int* buckets = rowptrS + NSUP * 513;
    h16* WF      = (h16*)(buckets + (size_t)NSUP * SB_CAP);
    h16* W1aF = WF;               // order: W1a, W1b, W2a, W2b, W3a, W3b
    h16* W1bF = WF + 4096 * 1;
    h16* W2aF = WF + 4096 * 2;
    h16* W2bF = WF + 4096 * 3;
    h16* W3aF = WF + 4096 * 4;
    h16* W3bF = WF + 4096 * 5;

    hipMemsetAsync(cnt, 0, NSUP * sizeof(int), stream);
    // partition || wprep || input-linear in one dispatch
    k_fat<<<NPB + NWP + TILE2, 256, 0, stream>>>(src, dst, cnt, buckets,
        W1a, W1b, W2a, W2b, W3a, W3b, WF, W0, b0, x, HA);
    k_sort<<<NSUP, 256, 0, stream>>>(cnt, buckets, rowptrS);

    k_aggregate<<<AGG_BLOCKS, 256, 0, stream>>>(rowptrS, buckets, HA, Z);
    k_mlp<<<TILE2, 256, 0, stream>>>(W1aF, b1a, W1bF, b1b, Z, HA);

    k_aggregate<<<AGG_BLOCKS, 256, 0, stream>>>(rowptrS, buckets, HA, Z);
    k_mlp<<<TILE2, 256, 0, stream>>>(W2aF, b2a, W2bF, b2b, Z, HA);

    k_aggregate<<<AGG_BLOCKS, 256, 0, stream>>>(rowptrS, buckets, HA, Z);
    k_mlp<<<TILE2, 256, 0, stream>>>(W3aF, b3a, W3bF, b3b, Z, HA);

    k_poolfinal<<<N_GRAPHS, 256, 0, stream>>>(HA, batch, Wl, bl, out);
}